// Round 15
// baseline (84.412 us; speedup 1.0000x reference)
//
#include <hip/hip_runtime.h>

#define BB 4
#define TT 512
#define HH 512
#define UU 256

// 2*log2(e): e^{2x} = 2^{c*x}
#define C2L2E 2.8853900817779268f
#define L2E   1.4426950408889634f

typedef __attribute__((ext_vector_type(8))) short bf16x8;
typedef __attribute__((ext_vector_type(4))) float f32x4;

static __device__ inline unsigned short f2bf(float x) {
    union { float f; unsigned u; } v; v.f = x;
    unsigned r = v.u + 0x7fff + ((v.u >> 16) & 1);   // RNE
    return (unsigned short)(r >> 16);
}

// ---------------- prep (513 blocks) ----------------
// blocks 0..255   : h -> bf16 (float4 -> ushort4, coalesced)
// blocks 256..511 : WcatT[n][k] = bf16(c*W{q,k}[k][n]) via LDS 32x32 tile transpose
// block 512       : w2/cbq/scal + zero denom/wsum/out
__global__ __launch_bounds__(256) void prep_kernel(const float* __restrict__ h,
                                                   const float* __restrict__ Wq,
                                                   const float* __restrict__ Wk,
                                                   const float* __restrict__ bq,
                                                   const float* __restrict__ W,
                                                   const float* __restrict__ b_alpha,
                                                   unsigned short* __restrict__ hbf,
                                                   unsigned short* __restrict__ WcatT,
                                                   float* __restrict__ cbq,
                                                   float* __restrict__ w2,
                                                   float* __restrict__ scal,
                                                   float* __restrict__ denom,
                                                   float* __restrict__ wsum,
                                                   float* __restrict__ out)
{
    const int blk = blockIdx.x;
    const int tid = threadIdx.x;

    if (blk < 256) {
        const int gid = blk * 256 + tid;                  // 65536 threads
#pragma unroll
        for (int it = 0; it < 4; ++it) {
            const int i = gid + it * 65536;               // 262144 float4 total
            const float4 v = ((const float4*)h)[i];
            ushort4 o;
            o.x = f2bf(v.x); o.y = f2bf(v.y); o.z = f2bf(v.z); o.w = f2bf(v.w);
            ((ushort4*)hbf)[i] = o;
        }
    } else if (blk < 512) {
        __shared__ unsigned short lds[32][33];
        const int tile = blk - 256;                       // 0..255
        const int tn = tile & 15;                         // n-tile
        const int tk = tile >> 4;                         // k-tile
        const int lx = tid & 31;
        const int ly = tid >> 5;                          // 0..7
        const int n = tn * 32 + lx;
#pragma unroll
        for (int kk = ly; kk < 32; kk += 8) {
            const int k = tk * 32 + kk;
            const float v = (n < 256) ? Wq[k * UU + n] : Wk[k * UU + (n - 256)];
            lds[lx][kk] = f2bf(C2L2E * v);
        }
        __syncthreads();
#pragma unroll
        for (int nn = ly; nn < 32; nn += 8) {
            WcatT[(size_t)(tn * 32 + nn) * 512 + tk * 32 + lx] = lds[nn][lx];
        }
    } else {
        __shared__ float red[256];
        const float w = W[tid];
        w2[tid] = -2.0f * w;
        red[tid] = w;
        cbq[tid] = C2L2E * bq[tid];
        __syncthreads();
        for (int off = 128; off > 0; off >>= 1) {
            if (tid < off) red[tid] += red[tid + off];
            __syncthreads();
        }
        if (tid == 0) { scal[0] = red[0]; scal[1] = b_alpha[0]; }
#pragma unroll
        for (int it = 0; it < 8; ++it) {
            const int i = tid + it * 256;                 // 2048
            denom[i] = 0.0f; wsum[i] = 0.0f; out[i] = 0.0f;
        }
    }
}

// ---------------- kernel 1: bf16 MFMA GEMM + exp2 epilogue (unchanged) ----------------
__global__ __launch_bounds__(256) void qk_mfma(const unsigned short* __restrict__ hbf,
                                               const unsigned short* __restrict__ WcatT,
                                               const float* __restrict__ cbq,
                                               float* __restrict__ EQ,
                                               float* __restrict__ EKm)
{
    const int wave = (blockIdx.x * 256 + threadIdx.x) >> 6;   // 0..2047
    const int lane = threadIdx.x & 63;
    const int mt = wave >> 4;          // 0..127
    const int nt = wave & 15;          // 0..15
    const int m0 = mt * 16, n0 = nt * 32;
    const int lrow = lane & 15;
    const int kgrp = lane >> 4;        // 0..3

    f32x4 acc0 = {0.f, 0.f, 0.f, 0.f};
    f32x4 acc1 = {0.f, 0.f, 0.f, 0.f};
    const unsigned short* Arow = hbf   + (size_t)(m0 + lrow) * 512 + kgrp * 8;
    const unsigned short* B0   = WcatT + (size_t)(n0 + lrow) * 512 + kgrp * 8;
    const unsigned short* B1   = B0 + (size_t)16 * 512;

#pragma unroll
    for (int k0 = 0; k0 < 512; k0 += 32) {
        const bf16x8 a  = *(const bf16x8*)(Arow + k0);
        const bf16x8 b0 = *(const bf16x8*)(B0 + k0);
        const bf16x8 b1 = *(const bf16x8*)(B1 + k0);
        acc0 = __builtin_amdgcn_mfma_f32_16x16x32_bf16(a, b0, acc0, 0, 0, 0);
        acc1 = __builtin_amdgcn_mfma_f32_16x16x32_bf16(a, b1, acc1, 0, 0, 0);
    }

    const int n_0 = n0 + lrow;
    const int n_1 = n_0 + 16;
    if (nt < 8) {
#pragma unroll
        for (int r = 0; r < 4; r++) {
            const int m = m0 + kgrp * 4 + r;
            EQ[(size_t)(n_0 >> 2) * 8192 + m * 4 + (n_0 & 3)] = __builtin_amdgcn_exp2f(acc0[r]);
            EQ[(size_t)(n_1 >> 2) * 8192 + m * 4 + (n_1 & 3)] = __builtin_amdgcn_exp2f(acc1[r]);
        }
    } else {
        const float bias0 = cbq[n_0 - 256];
        const float bias1 = cbq[n_1 - 256];
#pragma unroll
        for (int r = 0; r < 4; r++) {
            const int m = m0 + kgrp * 4 + r;
            EKm[(size_t)m * 256 + (n_0 - 256)] = __builtin_amdgcn_exp2f(acc0[r] + bias0);
            EKm[(size_t)m * 256 + (n_1 - 256)] = __builtin_amdgcn_exp2f(acc1[r] + bias1);
        }
    }
}

// ---------------- kernel 2a: scores + sigmoid + exp, per-(b,t) denom ----------------
// grid (sg=256, tg=2, b=4) = 2048 blocks x 256 threads (4 waves) -> 8 blocks/CU,
// 8 waves/SIMD, one fully-resident round. Wave wv owns u-slice [64*wv, 64*wv+64).
// lane = t, FOUR t-streams. Block: 256 t x 2 s. LDS = 2KB khk + 8KB part = 10 KB.
// Inner math pure scalar t-form (R14, verified):
//   pair: (w_a*t_b + w_b*t_a)/(t_a*t_b), t = fmaf(h,k,1); quad combines two pairs, 1 rcp.
__global__ __launch_bounds__(256, 8) void score_kernel(const float* __restrict__ EQ,
                                                       const float* __restrict__ EKm,
                                                       const float* __restrict__ w2,
                                                       const float* __restrict__ scal,
                                                       float* __restrict__ E,
                                                       float* __restrict__ denom)
{
    const int b  = blockIdx.z;
    const int tg = blockIdx.y;          // 0..1 (256 t per block)
    const int sg = blockIdx.x;          // 0..255 (2 s per block)
    const int tid  = threadIdx.x;       // 0..255
    const int lane = tid & 63;
    const int wv = __builtin_amdgcn_readfirstlane((int)(tid >> 6));  // 0..3 = u-slice owner
    const int gbase = b * TT + tg * 256;
    const int g0 = gbase + lane;

    __shared__ __align__(16) float khk [2 * 256];          // ek rows (2 s), 2 KB
    __shared__ __align__(16) float part[2 * 4 * 4 * 64];   // [s][st][wv][lane], 8 KB

    {   // stage ek, coalesced: 2 rows x 256 floats = 128 float4
        if (tid < 128) {
            const int flat = tid * 4;          // 0..511
            const int s = flat >> 8;
            const int u = flat & 255;
            *(float4*)&khk[flat] = *(const float4*)(EKm + (size_t)(b * TT + sg * 2 + s) * 256 + u);
        }
    }
    __syncthreads();

    float acc[2][4];   // [s][st]
#pragma unroll
    for (int s = 0; s < 2; ++s)
#pragma unroll
        for (int st = 0; st < 4; ++st) acc[s][st] = 0.0f;

    for (int sub = 0; sub < 8; ++sub) {
        const int q0 = wv * 16 + sub * 2;   // global quad index (2 quads = 8 u per sub)

        // wave-uniform weights (s_load)
        float w[2][4];
#pragma unroll
        for (int q = 0; q < 2; ++q)
#pragma unroll
            for (int j = 0; j < 4; ++j) w[q][j] = w2[(q0 + q) * 4 + j];

        // hq: 4 streams x 2 quads, coalesced b128
        f32x4 hq[4][2];
#pragma unroll
        for (int st = 0; st < 4; ++st)
#pragma unroll
            for (int q = 0; q < 2; ++q)
                hq[st][q] = *(const f32x4*)(EQ + (size_t)(q0 + q) * 8192 + (size_t)(g0 + st * 64) * 4);

#pragma unroll
        for (int s = 0; s < 2; ++s) {
#pragma unroll
            for (int q = 0; q < 2; ++q) {
                const f32x4 ekv = *(const f32x4*)&khk[s * 256 + (q0 + q) * 4];
#pragma unroll
                for (int st = 0; st < 4; ++st) {
                    const f32x4 hv = hq[st][q];
                    const float t0 = fmaf(hv[0], ekv[0], 1.0f);
                    const float t1 = fmaf(hv[1], ekv[1], 1.0f);
                    const float t2 = fmaf(hv[2], ekv[2], 1.0f);
                    const float t3 = fmaf(hv[3], ekv[3], 1.0f);
                    const float d01 = t0 * t1;
                    const float d23 = t2 * t3;
                    const float n01 = fmaf(w[q][0], t1, w[q][1] * t0);
                    const float n23 = fmaf(w[q][2], t3, w[q][3] * t2);
                    const float dq  = d01 * d23;
                    const float nq  = fmaf(n01, d23, n23 * d01);
                    const float r   = __builtin_amdgcn_rcpf(dq);
                    acc[s][st] = fmaf(nq, r, acc[s][st]);
                }
            }
        }
    }

    // write u-slice partials (lane-contiguous, conflict-free)
#pragma unroll
    for (int s = 0; s < 2; ++s)
#pragma unroll
        for (int st = 0; st < 4; ++st)
            part[((s * 4 + st) * 4 + wv) * 64 + lane] = acc[s][st];
    __syncthreads();

    // epilogue: thread tid owns t_local = tid (st = tid>>6, lane), both s
    const float sumW    = scal[0];
    const float b_alpha = scal[1];
    const int est = tid >> 6;
    float Ev[2];
    float psum = 0.0f;
#pragma unroll
    for (int s = 0; s < 2; ++s) {
        const float* pp = &part[(s * 4 + est) * 4 * 64 + lane];
        float z = pp[0] + pp[64] + pp[128] + pp[192] + sumW + b_alpha;
        const float sgm = __builtin_amdgcn_rcpf(1.0f + __builtin_amdgcn_exp2f(-z * L2E));
        Ev[s] = __builtin_amdgcn_exp2f(sgm * L2E);
        psum += Ev[s];
    }
    const int grow = gbase + tid;
    *(float2*)(E + (size_t)grow * TT + sg * 2) = make_float2(Ev[0], Ev[1]);
    atomicAdd(&denom[grow], psum);
}

// ---------------- kernel 2b: wsum[b,s] = (1/T) * sum_t E[b,t,s]/denom[b,t] ----------------
__global__ __launch_bounds__(256) void colsum_kernel(const float* __restrict__ E,
                                                     const float* __restrict__ denom,
                                                     float* __restrict__ wsum)
{
    const int b  = blockIdx.y;
    const int t0 = blockIdx.x * 8;
    const int s  = threadIdx.x;
    float a0 = 0.0f, a1 = 0.0f;
#pragma unroll
    for (int ti = 0; ti < 8; ++ti) {
        const int t = t0 + ti;
        const float rd = __builtin_amdgcn_rcpf(denom[b * TT + t]);
        const float* __restrict__ Er = E + (size_t)(b * TT + t) * TT;
        a0 = fmaf(Er[s],       rd, a0);
        a1 = fmaf(Er[s + 256], rd, a1);
    }
    atomicAdd(&wsum[b * TT + s],       a0 * (1.0f / TT));
    atomicAdd(&wsum[b * TT + s + 256], a1 * (1.0f / TT));
}

// ---------------- kernel 3: out[b,:] = sum_s wsum[b,s] * h[b,s,:] ----------------
__global__ __launch_bounds__(512) void ctx_kernel(const float* __restrict__ h,
                                                  const float* __restrict__ wsum,
                                                  float* __restrict__ out)
{
    const int b  = blockIdx.y;
    const int s0 = blockIdx.x * 8;
    const int hd = threadIdx.x;
    float a = 0.0f;
#pragma unroll
    for (int si = 0; si < 8; ++si) {
        const int s = s0 + si;
        a = fmaf(wsum[b * TT + s], h[(size_t)(b * TT + s) * HH + hd], a);
    }
    atomicAdd(&out[b * HH + hd], a);
}

extern "C" void kernel_launch(void* const* d_in, const int* in_sizes, int n_in,
                              void* d_out, int out_size, void* d_ws, size_t ws_size,
                              hipStream_t stream)
{
    const float* h       = (const float*)d_in[0];
    const float* Wq      = (const float*)d_in[1];
    const float* Wk      = (const float*)d_in[2];
    const float* bq      = (const float*)d_in[3];
    const float* W       = (const float*)d_in[4];
    const float* b_alpha = (const float*)d_in[5];
    float* out = (float*)d_out;

    float* ws    = (float*)d_ws;
    float* EQ    = ws;                                   // 524,288 f32 (transposed quad-interleaved)
    float* EKm   = EQ + (size_t)524288;                  // 524,288 f32
    float* E     = EKm + (size_t)524288;                 // 1,048,576 f32
    float* denom = E + (size_t)1048576;                  // 2048
    float* wsum  = denom + BB * TT;                      // 2048
    float* w2    = wsum + BB * TT;                       // 256
    float* scal  = w2 + UU;                              // 2
    float* cbq   = scal + 2;                             // 256

    // bf16 staging aliases E (E is only written by score_kernel, after qk_mfma)
    unsigned short* hbf   = (unsigned short*)E;          // 1,048,576 bf16 = 2 MB
    unsigned short* WcatT = hbf + (size_t)1048576;       // 262,144 bf16 = 512 KB

    prep_kernel  <<<513, 256, 0, stream>>>(h, Wq, Wk, bq, W, b_alpha,
                                           hbf, WcatT, cbq, w2, scal, denom, wsum, out);
    qk_mfma      <<<512, 256, 0, stream>>>(hbf, WcatT, cbq, EQ, EKm);
    score_kernel <<<dim3(256, 2, BB), 256, 0, stream>>>(EQ, EKm, w2, scal, E, denom);
    colsum_kernel<<<dim3(64, BB), 256, 0, stream>>>(E, denom, wsum);
    ctx_kernel   <<<dim3(64, BB), 512, 0, stream>>>(h, wsum, out);
}

// Round 16
// 68.447 us; speedup vs baseline: 1.2333x; 1.2333x over previous
//
#include <hip/hip_runtime.h>

#define BB 4
#define TT 512
#define HH 512
#define UU 256

// 2*log2(e): e^{2x} = 2^{c*x}
#define C2L2E 2.8853900817779268f
#define L2E   1.4426950408889634f

typedef __attribute__((ext_vector_type(8))) short bf16x8;
typedef __attribute__((ext_vector_type(4))) float f32x4;

static __device__ inline unsigned short f2bf(float x) {
    union { float f; unsigned u; } v; v.f = x;
    unsigned r = v.u + 0x7fff + ((v.u >> 16) & 1);   // RNE
    return (unsigned short)(r >> 16);
}

// ---------------- prep (513 blocks) ----------------
__global__ __launch_bounds__(256) void prep_kernel(const float* __restrict__ h,
                                                   const float* __restrict__ Wq,
                                                   const float* __restrict__ Wk,
                                                   const float* __restrict__ bq,
                                                   const float* __restrict__ W,
                                                   const float* __restrict__ b_alpha,
                                                   unsigned short* __restrict__ hbf,
                                                   unsigned short* __restrict__ WcatT,
                                                   float* __restrict__ cbq,
                                                   float* __restrict__ w2,
                                                   float* __restrict__ scal,
                                                   float* __restrict__ denom,
                                                   float* __restrict__ wsum,
                                                   float* __restrict__ out)
{
    const int blk = blockIdx.x;
    const int tid = threadIdx.x;

    if (blk < 256) {
        const int gid = blk * 256 + tid;                  // 65536 threads
#pragma unroll
        for (int it = 0; it < 4; ++it) {
            const int i = gid + it * 65536;               // 262144 float4 total
            const float4 v = ((const float4*)h)[i];
            ushort4 o;
            o.x = f2bf(v.x); o.y = f2bf(v.y); o.z = f2bf(v.z); o.w = f2bf(v.w);
            ((ushort4*)hbf)[i] = o;
        }
    } else if (blk < 512) {
        __shared__ unsigned short lds[32][33];
        const int tile = blk - 256;                       // 0..255
        const int tn = tile & 15;                         // n-tile
        const int tk = tile >> 4;                         // k-tile
        const int lx = tid & 31;
        const int ly = tid >> 5;                          // 0..7
        const int n = tn * 32 + lx;
#pragma unroll
        for (int kk = ly; kk < 32; kk += 8) {
            const int k = tk * 32 + kk;
            const float v = (n < 256) ? Wq[k * UU + n] : Wk[k * UU + (n - 256)];
            lds[lx][kk] = f2bf(C2L2E * v);
        }
        __syncthreads();
#pragma unroll
        for (int nn = ly; nn < 32; nn += 8) {
            WcatT[(size_t)(tn * 32 + nn) * 512 + tk * 32 + lx] = lds[nn][lx];
        }
    } else {
        __shared__ float red[256];
        const float w = W[tid];
        w2[tid] = -2.0f * w;
        red[tid] = w;
        cbq[tid] = C2L2E * bq[tid];
        __syncthreads();
        for (int off = 128; off > 0; off >>= 1) {
            if (tid < off) red[tid] += red[tid + off];
            __syncthreads();
        }
        if (tid == 0) { scal[0] = red[0]; scal[1] = b_alpha[0]; }
#pragma unroll
        for (int it = 0; it < 8; ++it) {
            const int i = tid + it * 256;                 // 2048
            denom[i] = 0.0f; wsum[i] = 0.0f; out[i] = 0.0f;
        }
    }
}

// ---------------- kernel 1: bf16 MFMA GEMM + exp2 epilogue (unchanged) ----------------
__global__ __launch_bounds__(256) void qk_mfma(const unsigned short* __restrict__ hbf,
                                               const unsigned short* __restrict__ WcatT,
                                               const float* __restrict__ cbq,
                                               float* __restrict__ EQ,
                                               float* __restrict__ EKm)
{
    const int wave = (blockIdx.x * 256 + threadIdx.x) >> 6;   // 0..2047
    const int lane = threadIdx.x & 63;
    const int mt = wave >> 4;          // 0..127
    const int nt = wave & 15;          // 0..15
    const int m0 = mt * 16, n0 = nt * 32;
    const int lrow = lane & 15;
    const int kgrp = lane >> 4;        // 0..3

    f32x4 acc0 = {0.f, 0.f, 0.f, 0.f};
    f32x4 acc1 = {0.f, 0.f, 0.f, 0.f};
    const unsigned short* Arow = hbf   + (size_t)(m0 + lrow) * 512 + kgrp * 8;
    const unsigned short* B0   = WcatT + (size_t)(n0 + lrow) * 512 + kgrp * 8;
    const unsigned short* B1   = B0 + (size_t)16 * 512;

#pragma unroll
    for (int k0 = 0; k0 < 512; k0 += 32) {
        const bf16x8 a  = *(const bf16x8*)(Arow + k0);
        const bf16x8 b0 = *(const bf16x8*)(B0 + k0);
        const bf16x8 b1 = *(const bf16x8*)(B1 + k0);
        acc0 = __builtin_amdgcn_mfma_f32_16x16x32_bf16(a, b0, acc0, 0, 0, 0);
        acc1 = __builtin_amdgcn_mfma_f32_16x16x32_bf16(a, b1, acc1, 0, 0, 0);
    }

    const int n_0 = n0 + lrow;
    const int n_1 = n_0 + 16;
    if (nt < 8) {
#pragma unroll
        for (int r = 0; r < 4; r++) {
            const int m = m0 + kgrp * 4 + r;
            EQ[(size_t)(n_0 >> 2) * 8192 + m * 4 + (n_0 & 3)] = __builtin_amdgcn_exp2f(acc0[r]);
            EQ[(size_t)(n_1 >> 2) * 8192 + m * 4 + (n_1 & 3)] = __builtin_amdgcn_exp2f(acc1[r]);
        }
    } else {
        const float bias0 = cbq[n_0 - 256];
        const float bias1 = cbq[n_1 - 256];
#pragma unroll
        for (int r = 0; r < 4; r++) {
            const int m = m0 + kgrp * 4 + r;
            EKm[(size_t)m * 256 + (n_0 - 256)] = __builtin_amdgcn_exp2f(acc0[r] + bias0);
            EKm[(size_t)m * 256 + (n_1 - 256)] = __builtin_amdgcn_exp2f(acc1[r] + bias1);
        }
    }
}

// ---------------- kernel 2a: scores + sigmoid + exp, per-(b,t) denom ----------------
// R14 config: grid (sg=128, tg=2, b=4) = 1024 blocks x 4 waves, 4 blocks/CU.
// Wave wv owns u-slice [64*wv, 64*wv+64). lane = t, FOUR t-streams. Block: 256 t x 4 s.
// Pure scalar t-form quad-rational. NEW: 2x sub-unroll with A/B hq double buffers (plain C).

#define LOAD_HQ(dst, subv) do {                                                          \
    const int q0_ = wv * 16 + (subv) * 2;                                                \
    _Pragma("unroll") for (int st_ = 0; st_ < 4; ++st_)                                  \
        _Pragma("unroll") for (int q_ = 0; q_ < 2; ++q_)                                 \
            dst[st_][q_] = *(const f32x4*)(EQ + (size_t)(q0_ + q_) * 8192                \
                                              + (size_t)(g0 + st_ * 64) * 4);           \
} while (0)

#define COMPUTE_SUB(hqbuf, subv) do {                                                    \
    const int q0_ = wv * 16 + (subv) * 2;                                                \
    float w_[2][4];                                                                      \
    _Pragma("unroll") for (int q_ = 0; q_ < 2; ++q_)                                     \
        _Pragma("unroll") for (int j_ = 0; j_ < 4; ++j_)                                 \
            w_[q_][j_] = w2[(q0_ + q_) * 4 + j_];                                        \
    _Pragma("unroll") for (int s_ = 0; s_ < 4; ++s_) {                                   \
        _Pragma("unroll") for (int q_ = 0; q_ < 2; ++q_) {                               \
            const f32x4 ekv_ = *(const f32x4*)&khk[s_ * 256 + (q0_ + q_) * 4];           \
            _Pragma("unroll") for (int st_ = 0; st_ < 4; ++st_) {                        \
                const f32x4 hv_ = hqbuf[st_][q_];                                        \
                const float t0_ = fmaf(hv_[0], ekv_[0], 1.0f);                           \
                const float t1_ = fmaf(hv_[1], ekv_[1], 1.0f);                           \
                const float t2_ = fmaf(hv_[2], ekv_[2], 1.0f);                           \
                const float t3_ = fmaf(hv_[3], ekv_[3], 1.0f);                           \
                const float d01_ = t0_ * t1_;                                            \
                const float d23_ = t2_ * t3_;                                            \
                const float n01_ = fmaf(w_[q_][0], t1_, w_[q_][1] * t0_);                \
                const float n23_ = fmaf(w_[q_][2], t3_, w_[q_][3] * t2_);                \
                const float dq_  = d01_ * d23_;                                          \
                const float nq_  = fmaf(n01_, d23_, n23_ * d01_);                        \
                const float r_   = __builtin_amdgcn_rcpf(dq_);                           \
                acc[s_][st_] = fmaf(nq_, r_, acc[s_][st_]);                              \
            }                                                                            \
        }                                                                                \
    }                                                                                    \
} while (0)

__global__ __launch_bounds__(256, 4) void score_kernel(const float* __restrict__ EQ,
                                                       const float* __restrict__ EKm,
                                                       const float* __restrict__ w2,
                                                       const float* __restrict__ scal,
                                                       float* __restrict__ E,
                                                       float* __restrict__ denom)
{
    const int b  = blockIdx.z;
    const int tg = blockIdx.y;          // 0..1 (256 t per block)
    const int sg = blockIdx.x;          // 0..127 (4 s per block)
    const int tid  = threadIdx.x;       // 0..255
    const int lane = tid & 63;
    const int wv = __builtin_amdgcn_readfirstlane((int)(tid >> 6));  // 0..3 = u-slice owner
    const int gbase = b * TT + tg * 256;
    const int g0 = gbase + lane;

    __shared__ __align__(16) float khk [4 * 256];          // ek rows (4 s), 4 KB
    __shared__ __align__(16) float part[4 * 4 * 4 * 64];   // [s][st][wv][lane], 16 KB

    {   // stage ek, coalesced: 4 rows x 256 floats
        const int flat = tid * 4;          // 0..1023
        const int s = flat >> 8;
        const int u = flat & 255;
        *(float4*)&khk[flat] = *(const float4*)(EKm + (size_t)(b * TT + sg * 4 + s) * 256 + u);
    }
    __syncthreads();

    float acc[4][4];   // [s][st]
#pragma unroll
    for (int s = 0; s < 4; ++s)
#pragma unroll
        for (int st = 0; st < 4; ++st) acc[s][st] = 0.0f;

    f32x4 hqA[4][2], hqB[4][2];
    LOAD_HQ(hqA, 0);
    for (int sp = 0; sp < 4; ++sp) {
        LOAD_HQ(hqB, 2 * sp + 1);
        COMPUTE_SUB(hqA, 2 * sp);
        if (sp < 3) LOAD_HQ(hqA, 2 * sp + 2);
        COMPUTE_SUB(hqB, 2 * sp + 1);
    }

    // write u-slice partials (lane-contiguous, conflict-free)
#pragma unroll
    for (int s = 0; s < 4; ++s)
#pragma unroll
        for (int st = 0; st < 4; ++st)
            part[((s * 4 + st) * 4 + wv) * 64 + lane] = acc[s][st];
    __syncthreads();

    // epilogue: thread tid owns t_local = tid (st = tid>>6, lane), all 4 s
    const float sumW    = scal[0];
    const float b_alpha = scal[1];
    const int est = tid >> 6;
    float Ev[4];
    float psum = 0.0f;
#pragma unroll
    for (int s = 0; s < 4; ++s) {
        const float* pp = &part[(s * 4 + est) * 4 * 64 + lane];
        float z = pp[0] + pp[64] + pp[128] + pp[192] + sumW + b_alpha;
        const float sgm = __builtin_amdgcn_rcpf(1.0f + __builtin_amdgcn_exp2f(-z * L2E));
        Ev[s] = __builtin_amdgcn_exp2f(sgm * L2E);
        psum += Ev[s];
    }
    const int grow = gbase + tid;
    *(float4*)(E + (size_t)grow * TT + sg * 4) = make_float4(Ev[0], Ev[1], Ev[2], Ev[3]);
    atomicAdd(&denom[grow], psum);
}

// ---------------- kernel 2b: wsum[b,s] = (1/T) * sum_t E[b,t,s]/denom[b,t] ----------------
__global__ __launch_bounds__(256) void colsum_kernel(const float* __restrict__ E,
                                                     const float* __restrict__ denom,
                                                     float* __restrict__ wsum)
{
    const int b  = blockIdx.y;
    const int t0 = blockIdx.x * 4;
    const int s  = threadIdx.x;
    float a0 = 0.0f, a1 = 0.0f;
#pragma unroll
    for (int ti = 0; ti < 4; ++ti) {
        const int t = t0 + ti;
        const float rd = __builtin_amdgcn_rcpf(denom[b * TT + t]);
        const float* __restrict__ Er = E + (size_t)(b * TT + t) * TT;
        a0 = fmaf(Er[s],       rd, a0);
        a1 = fmaf(Er[s + 256], rd, a1);
    }
    atomicAdd(&wsum[b * TT + s],       a0 * (1.0f / TT));
    atomicAdd(&wsum[b * TT + s + 256], a1 * (1.0f / TT));
}

// ---------------- kernel 3: out[b,:] = sum_s wsum[b,s] * h[b,s,:] ----------------
__global__ __launch_bounds__(512) void ctx_kernel(const float* __restrict__ h,
                                                  const float* __restrict__ wsum,
                                                  float* __restrict__ out)
{
    const int b  = blockIdx.y;
    const int s0 = blockIdx.x * 8;
    const int hd = threadIdx.x;
    float a = 0.0f;
#pragma unroll
    for (int si = 0; si < 8; ++si) {
        const int s = s0 + si;
        a = fmaf(wsum[b * TT + s], h[(size_t)(b * TT + s) * HH + hd], a);
    }
    atomicAdd(&out[b * HH + hd], a);
}

extern "C" void kernel_launch(void* const* d_in, const int* in_sizes, int n_in,
                              void* d_out, int out_size, void* d_ws, size_t ws_size,
                              hipStream_t stream)
{
    const float* h       = (const float*)d_in[0];
    const float* Wq      = (const float*)d_in[1];
    const float* Wk      = (const float*)d_in[2];
    const float* bq      = (const float*)d_in[3];
    const float* W       = (const float*)d_in[4];
    const float* b_alpha = (const float*)d_in[5];
    float* out = (float*)d_out;

    float* ws    = (float*)d_ws;
    float* EQ    = ws;                                   // 524,288 f32 (transposed quad-interleaved)
    float* EKm   = EQ + (size_t)524288;                  // 524,288 f32
    float* E     = EKm + (size_t)524288;                 // 1,048,576 f32
    float* denom = E + (size_t)1048576;                  // 2048
    float* wsum  = denom + BB * TT;                      // 2048
    float* w2    = wsum + BB * TT;                       // 256
    float* scal  = w2 + UU;                              // 2
    float* cbq   = scal + 2;                             // 256

    // bf16 staging aliases E (E is only written by score_kernel, after qk_mfma)
    unsigned short* hbf   = (unsigned short*)E;          // 1,048,576 bf16 = 2 MB
    unsigned short* WcatT = hbf + (size_t)1048576;       // 262,144 bf16 = 512 KB

    prep_kernel  <<<513, 256, 0, stream>>>(h, Wq, Wk, bq, W, b_alpha,
                                           hbf, WcatT, cbq, w2, scal, denom, wsum, out);
    qk_mfma      <<<512, 256, 0, stream>>>(hbf, WcatT, cbq, EQ, EKm);
    score_kernel <<<dim3(128, 2, BB), 256, 0, stream>>>(EQ, EKm, w2, scal, E, denom);
    colsum_kernel<<<dim3(128, BB), 256, 0, stream>>>(E, denom, wsum);
    ctx_kernel   <<<dim3(64, BB), 512, 0, stream>>>(h, wsum, out);
}

// Round 17
// 66.600 us; speedup vs baseline: 1.2675x; 1.0277x over previous
//
#include <hip/hip_runtime.h>

#define BB 4
#define TT 512
#define HH 512
#define UU 256

// 2*log2(e): e^{2x} = 2^{c*x}
#define C2L2E 2.8853900817779268f
#define L2E   1.4426950408889634f

typedef __attribute__((ext_vector_type(8))) short bf16x8;
typedef __attribute__((ext_vector_type(4))) float f32x4;

static __device__ inline unsigned short f2bf(float x) {
    union { float f; unsigned u; } v; v.f = x;
    unsigned r = v.u + 0x7fff + ((v.u >> 16) & 1);   // RNE
    return (unsigned short)(r >> 16);
}

// ---------------- prep (513 blocks) ----------------
// blocks 0..255   : h -> bf16 (float4 -> ushort4, coalesced)
// blocks 256..511 : WcatT[n][k] = bf16(c*W{q,k}[k][n]) via LDS 32x32 tile transpose
// block 512       : w2/cbq/scal + zero denom/wsum/out
__global__ __launch_bounds__(256) void prep_kernel(const float* __restrict__ h,
                                                   const float* __restrict__ Wq,
                                                   const float* __restrict__ Wk,
                                                   const float* __restrict__ bq,
                                                   const float* __restrict__ W,
                                                   const float* __restrict__ b_alpha,
                                                   unsigned short* __restrict__ hbf,
                                                   unsigned short* __restrict__ WcatT,
                                                   float* __restrict__ cbq,
                                                   float* __restrict__ w2,
                                                   float* __restrict__ scal,
                                                   float* __restrict__ denom,
                                                   float* __restrict__ wsum,
                                                   float* __restrict__ out)
{
    const int blk = blockIdx.x;
    const int tid = threadIdx.x;

    if (blk < 256) {
        const int gid = blk * 256 + tid;                  // 65536 threads
#pragma unroll
        for (int it = 0; it < 4; ++it) {
            const int i = gid + it * 65536;               // 262144 float4 total
            const float4 v = ((const float4*)h)[i];
            ushort4 o;
            o.x = f2bf(v.x); o.y = f2bf(v.y); o.z = f2bf(v.z); o.w = f2bf(v.w);
            ((ushort4*)hbf)[i] = o;
        }
    } else if (blk < 512) {
        __shared__ unsigned short lds[32][33];
        const int tile = blk - 256;                       // 0..255
        const int tn = tile & 15;                         // n-tile
        const int tk = tile >> 4;                         // k-tile
        const int lx = tid & 31;
        const int ly = tid >> 5;                          // 0..7
        const int n = tn * 32 + lx;
#pragma unroll
        for (int kk = ly; kk < 32; kk += 8) {
            const int k = tk * 32 + kk;
            const float v = (n < 256) ? Wq[k * UU + n] : Wk[k * UU + (n - 256)];
            lds[lx][kk] = f2bf(C2L2E * v);
        }
        __syncthreads();
#pragma unroll
        for (int nn = ly; nn < 32; nn += 8) {
            WcatT[(size_t)(tn * 32 + nn) * 512 + tk * 32 + lx] = lds[nn][lx];
        }
    } else {
        __shared__ float red[256];
        const float w = W[tid];
        w2[tid] = -2.0f * w;
        red[tid] = w;
        cbq[tid] = C2L2E * bq[tid];
        __syncthreads();
        for (int off = 128; off > 0; off >>= 1) {
            if (tid < off) red[tid] += red[tid + off];
            __syncthreads();
        }
        if (tid == 0) { scal[0] = red[0]; scal[1] = b_alpha[0]; }
#pragma unroll
        for (int it = 0; it < 8; ++it) {
            const int i = tid + it * 256;                 // 2048
            denom[i] = 0.0f; wsum[i] = 0.0f; out[i] = 0.0f;
        }
    }
}

// ---------------- kernel 1: bf16 MFMA GEMM + exp2 epilogue (unchanged) ----------------
__global__ __launch_bounds__(256) void qk_mfma(const unsigned short* __restrict__ hbf,
                                               const unsigned short* __restrict__ WcatT,
                                               const float* __restrict__ cbq,
                                               float* __restrict__ EQ,
                                               float* __restrict__ EKm)
{
    const int wave = (blockIdx.x * 256 + threadIdx.x) >> 6;   // 0..2047
    const int lane = threadIdx.x & 63;
    const int mt = wave >> 4;          // 0..127
    const int nt = wave & 15;          // 0..15
    const int m0 = mt * 16, n0 = nt * 32;
    const int lrow = lane & 15;
    const int kgrp = lane >> 4;        // 0..3

    f32x4 acc0 = {0.f, 0.f, 0.f, 0.f};
    f32x4 acc1 = {0.f, 0.f, 0.f, 0.f};
    const unsigned short* Arow = hbf   + (size_t)(m0 + lrow) * 512 + kgrp * 8;
    const unsigned short* B0   = WcatT + (size_t)(n0 + lrow) * 512 + kgrp * 8;
    const unsigned short* B1   = B0 + (size_t)16 * 512;

#pragma unroll
    for (int k0 = 0; k0 < 512; k0 += 32) {
        const bf16x8 a  = *(const bf16x8*)(Arow + k0);
        const bf16x8 b0 = *(const bf16x8*)(B0 + k0);
        const bf16x8 b1 = *(const bf16x8*)(B1 + k0);
        acc0 = __builtin_amdgcn_mfma_f32_16x16x32_bf16(a, b0, acc0, 0, 0, 0);
        acc1 = __builtin_amdgcn_mfma_f32_16x16x32_bf16(a, b1, acc1, 0, 0, 0);
    }

    const int n_0 = n0 + lrow;
    const int n_1 = n_0 + 16;
    if (nt < 8) {
#pragma unroll
        for (int r = 0; r < 4; r++) {
            const int m = m0 + kgrp * 4 + r;
            EQ[(size_t)(n_0 >> 2) * 8192 + m * 4 + (n_0 & 3)] = __builtin_amdgcn_exp2f(acc0[r]);
            EQ[(size_t)(n_1 >> 2) * 8192 + m * 4 + (n_1 & 3)] = __builtin_amdgcn_exp2f(acc1[r]);
        }
    } else {
        const float bias0 = cbq[n_0 - 256];
        const float bias1 = cbq[n_1 - 256];
#pragma unroll
        for (int r = 0; r < 4; r++) {
            const int m = m0 + kgrp * 4 + r;
            EKm[(size_t)m * 256 + (n_0 - 256)] = __builtin_amdgcn_exp2f(acc0[r] + bias0);
            EKm[(size_t)m * 256 + (n_1 - 256)] = __builtin_amdgcn_exp2f(acc1[r] + bias1);
        }
    }
}

// ---------------- kernel 2a: scores + sigmoid + exp, per-(b,t) denom ----------------
// grid (sg=128, tg=4, b=4) = 2048 blocks x 256 threads (4 waves) -> 8 blocks/CU,
// 8 waves/SIMD, one fully-resident round, SAME per-(t,sg) EQ traffic as R14.
// Wave wv owns u-slice [64*wv, 64*wv+64). lane = t, TWO t-streams (t, t+64).
// Block: 128 t x 4 s. LDS = 4KB khk + 8KB part = 12 KB -> 8 blocks/CU.
// Inner math pure scalar t-form (R14-verified):
//   pair: (w_a*t_b + w_b*t_a)/(t_a*t_b), t = fmaf(h,k,1); quad = 2 pairs, 1 rcp.
__global__ __launch_bounds__(256, 8) void score_kernel(const float* __restrict__ EQ,
                                                       const float* __restrict__ EKm,
                                                       const float* __restrict__ w2,
                                                       const float* __restrict__ scal,
                                                       float* __restrict__ E,
                                                       float* __restrict__ denom)
{
    const int b  = blockIdx.z;
    const int tg = blockIdx.y;          // 0..3 (128 t per block)
    const int sg = blockIdx.x;          // 0..127 (4 s per block)
    const int tid  = threadIdx.x;       // 0..255
    const int lane = tid & 63;
    const int wv = __builtin_amdgcn_readfirstlane((int)(tid >> 6));  // 0..3 = u-slice owner
    const int gbase = b * TT + tg * 128;
    const int g0 = gbase + lane;

    __shared__ __align__(16) float khk [4 * 256];          // ek rows (4 s), 4 KB
    __shared__ __align__(16) float part[4 * 2 * 4 * 64];   // [s][st][wv][lane], 8 KB

    {   // stage ek, coalesced: 4 rows x 256 floats
        const int flat = tid * 4;          // 0..1023
        const int s = flat >> 8;
        const int u = flat & 255;
        *(float4*)&khk[flat] = *(const float4*)(EKm + (size_t)(b * TT + sg * 4 + s) * 256 + u);
    }
    __syncthreads();

    float acc[4][2];   // [s][st]
#pragma unroll
    for (int s = 0; s < 4; ++s)
#pragma unroll
        for (int st = 0; st < 2; ++st) acc[s][st] = 0.0f;

    for (int sub = 0; sub < 8; ++sub) {
        const int q0 = wv * 16 + sub * 2;   // global quad index (2 quads = 8 u per sub)

        // wave-uniform weights (s_load)
        float w[2][4];
#pragma unroll
        for (int q = 0; q < 2; ++q)
#pragma unroll
            for (int j = 0; j < 4; ++j) w[q][j] = w2[(q0 + q) * 4 + j];

        // hq: 2 streams x 2 quads, coalesced b128
        f32x4 hq[2][2];
#pragma unroll
        for (int st = 0; st < 2; ++st)
#pragma unroll
            for (int q = 0; q < 2; ++q)
                hq[st][q] = *(const f32x4*)(EQ + (size_t)(q0 + q) * 8192 + (size_t)(g0 + st * 64) * 4);

#pragma unroll
        for (int s = 0; s < 4; ++s) {
#pragma unroll
            for (int q = 0; q < 2; ++q) {
                const f32x4 ekv = *(const f32x4*)&khk[s * 256 + (q0 + q) * 4];
#pragma unroll
                for (int st = 0; st < 2; ++st) {
                    const f32x4 hv = hq[st][q];
                    const float t0 = fmaf(hv[0], ekv[0], 1.0f);
                    const float t1 = fmaf(hv[1], ekv[1], 1.0f);
                    const float t2 = fmaf(hv[2], ekv[2], 1.0f);
                    const float t3 = fmaf(hv[3], ekv[3], 1.0f);
                    const float d01 = t0 * t1;
                    const float d23 = t2 * t3;
                    const float n01 = fmaf(w[q][0], t1, w[q][1] * t0);
                    const float n23 = fmaf(w[q][2], t3, w[q][3] * t2);
                    const float dq  = d01 * d23;
                    const float nq  = fmaf(n01, d23, n23 * d01);
                    const float r   = __builtin_amdgcn_rcpf(dq);
                    acc[s][st] = fmaf(nq, r, acc[s][st]);
                }
            }
        }
    }

    // write u-slice partials (lane-contiguous, conflict-free)
#pragma unroll
    for (int s = 0; s < 4; ++s)
#pragma unroll
        for (int st = 0; st < 2; ++st)
            part[((s * 2 + st) * 4 + wv) * 64 + lane] = acc[s][st];
    __syncthreads();

    // epilogue: t_local = tid & 127 (est = stream, li = lane); sh = tid>>7 -> s-pair
    const float sumW    = scal[0];
    const float b_alpha = scal[1];
    const int t_local = tid & 127;
    const int sh  = tid >> 7;          // 0..1 -> s pair {0,1} or {2,3}
    const int est = t_local >> 6;      // stream
    const int li  = t_local & 63;
    float Ev[2];
    float psum = 0.0f;
#pragma unroll
    for (int k = 0; k < 2; ++k) {
        const int s = sh * 2 + k;
        const float* pp = &part[(s * 2 + est) * 4 * 64 + li];
        float z = pp[0] + pp[64] + pp[128] + pp[192] + sumW + b_alpha;
        const float sgm = __builtin_amdgcn_rcpf(1.0f + __builtin_amdgcn_exp2f(-z * L2E));
        Ev[k] = __builtin_amdgcn_exp2f(sgm * L2E);
        psum += Ev[k];
    }
    const int grow = gbase + t_local;
    *(float2*)(E + (size_t)grow * TT + sg * 4 + sh * 2) = make_float2(Ev[0], Ev[1]);
    atomicAdd(&denom[grow], psum);
}

// ---------------- kernel 2b: wsum[b,s] = (1/T) * sum_t E[b,t,s]/denom[b,t] ----------------
__global__ __launch_bounds__(256) void colsum_kernel(const float* __restrict__ E,
                                                     const float* __restrict__ denom,
                                                     float* __restrict__ wsum)
{
    const int b  = blockIdx.y;
    const int t0 = blockIdx.x * 4;
    const int s  = threadIdx.x;
    float a0 = 0.0f, a1 = 0.0f;
#pragma unroll
    for (int ti = 0; ti < 4; ++ti) {
        const int t = t0 + ti;
        const float rd = __builtin_amdgcn_rcpf(denom[b * TT + t]);
        const float* __restrict__ Er = E + (size_t)(b * TT + t) * TT;
        a0 = fmaf(Er[s],       rd, a0);
        a1 = fmaf(Er[s + 256], rd, a1);
    }
    atomicAdd(&wsum[b * TT + s],       a0 * (1.0f / TT));
    atomicAdd(&wsum[b * TT + s + 256], a1 * (1.0f / TT));
}

// ---------------- kernel 3: out[b,:] = sum_s wsum[b,s] * h[b,s,:] ----------------
__global__ __launch_bounds__(512) void ctx_kernel(const float* __restrict__ h,
                                                  const float* __restrict__ wsum,
                                                  float* __restrict__ out)
{
    const int b  = blockIdx.y;
    const int s0 = blockIdx.x * 8;
    const int hd = threadIdx.x;
    float a = 0.0f;
#pragma unroll
    for (int si = 0; si < 8; ++si) {
        const int s = s0 + si;
        a = fmaf(wsum[b * TT + s], h[(size_t)(b * TT + s) * HH + hd], a);
    }
    atomicAdd(&out[b * HH + hd], a);
}

extern "C" void kernel_launch(void* const* d_in, const int* in_sizes, int n_in,
                              void* d_out, int out_size, void* d_ws, size_t ws_size,
                              hipStream_t stream)
{
    const float* h       = (const float*)d_in[0];
    const float* Wq      = (const float*)d_in[1];
    const float* Wk      = (const float*)d_in[2];
    const float* bq      = (const float*)d_in[3];
    const float* W       = (const float*)d_in[4];
    const float* b_alpha = (const float*)d_in[5];
    float* out = (float*)d_out;

    float* ws    = (float*)d_ws;
    float* EQ    = ws;                                   // 524,288 f32 (transposed quad-interleaved)
    float* EKm   = EQ + (size_t)524288;                  // 524,288 f32
    float* E     = EKm + (size_t)524288;                 // 1,048,576 f32
    float* denom = E + (size_t)1048576;                  // 2048
    float* wsum  = denom + BB * TT;                      // 2048
    float* w2    = wsum + BB * TT;                       // 256
    float* scal  = w2 + UU;                              // 2
    float* cbq   = scal + 2;                             // 256

    // bf16 staging aliases E (E is only written by score_kernel, after qk_mfma)
    unsigned short* hbf   = (unsigned short*)E;          // 1,048,576 bf16 = 2 MB
    unsigned short* WcatT = hbf + (size_t)1048576;       // 262,144 bf16 = 512 KB

    prep_kernel  <<<513, 256, 0, stream>>>(h, Wq, Wk, bq, W, b_alpha,
                                           hbf, WcatT, cbq, w2, scal, denom, wsum, out);
    qk_mfma      <<<512, 256, 0, stream>>>(hbf, WcatT, cbq, EQ, EKm);
    score_kernel <<<dim3(128, 4, BB), 256, 0, stream>>>(EQ, EKm, w2, scal, E, denom);
    colsum_kernel<<<dim3(128, BB), 256, 0, stream>>>(E, denom, wsum);
    ctx_kernel   <<<dim3(64, BB), 512, 0, stream>>>(h, wsum, out);
}

// Round 18
// 65.080 us; speedup vs baseline: 1.2970x; 1.0234x over previous
//
#include <hip/hip_runtime.h>

#define BB 4
#define TT 512
#define HH 512
#define UU 256

// 2*log2(e): e^{2x} = 2^{c*x}
#define C2L2E 2.8853900817779268f
#define L2E   1.4426950408889634f

typedef __attribute__((ext_vector_type(8))) short bf16x8;
typedef __attribute__((ext_vector_type(4))) float f32x4;

static __device__ inline unsigned short f2bf(float x) {
    union { float f; unsigned u; } v; v.f = x;
    unsigned r = v.u + 0x7fff + ((v.u >> 16) & 1);   // RNE
    return (unsigned short)(r >> 16);
}

// ---------------- prep (513 blocks) ----------------
// blocks 0..255   : h -> bf16 (float4 -> ushort4, coalesced)
// blocks 256..511 : WcatT[n][k] = bf16(c*W{q,k}[k][n]) via LDS 32x32 tile transpose
// block 512       : w2/cbq/scal + zero denom/wsum/out
__global__ __launch_bounds__(256) void prep_kernel(const float* __restrict__ h,
                                                   const float* __restrict__ Wq,
                                                   const float* __restrict__ Wk,
                                                   const float* __restrict__ bq,
                                                   const float* __restrict__ W,
                                                   const float* __restrict__ b_alpha,
                                                   unsigned short* __restrict__ hbf,
                                                   unsigned short* __restrict__ WcatT,
                                                   float* __restrict__ cbq,
                                                   float* __restrict__ w2,
                                                   float* __restrict__ scal,
                                                   float* __restrict__ denom,
                                                   float* __restrict__ wsum,
                                                   float* __restrict__ out)
{
    const int blk = blockIdx.x;
    const int tid = threadIdx.x;

    if (blk < 256) {
        const int gid = blk * 256 + tid;                  // 65536 threads
#pragma unroll
        for (int it = 0; it < 4; ++it) {
            const int i = gid + it * 65536;               // 262144 float4 total
            const float4 v = ((const float4*)h)[i];
            ushort4 o;
            o.x = f2bf(v.x); o.y = f2bf(v.y); o.z = f2bf(v.z); o.w = f2bf(v.w);
            ((ushort4*)hbf)[i] = o;
        }
    } else if (blk < 512) {
        __shared__ unsigned short lds[32][33];
        const int tile = blk - 256;                       // 0..255
        const int tn = tile & 15;                         // n-tile
        const int tk = tile >> 4;                         // k-tile
        const int lx = tid & 31;
        const int ly = tid >> 5;                          // 0..7
        const int n = tn * 32 + lx;
#pragma unroll
        for (int kk = ly; kk < 32; kk += 8) {
            const int k = tk * 32 + kk;
            const float v = (n < 256) ? Wq[k * UU + n] : Wk[k * UU + (n - 256)];
            lds[lx][kk] = f2bf(C2L2E * v);
        }
        __syncthreads();
#pragma unroll
        for (int nn = ly; nn < 32; nn += 8) {
            WcatT[(size_t)(tn * 32 + nn) * 512 + tk * 32 + lx] = lds[nn][lx];
        }
    } else {
        __shared__ float red[256];
        const float w = W[tid];
        w2[tid] = -2.0f * w;
        red[tid] = w;
        cbq[tid] = C2L2E * bq[tid];
        __syncthreads();
        for (int off = 128; off > 0; off >>= 1) {
            if (tid < off) red[tid] += red[tid + off];
            __syncthreads();
        }
        if (tid == 0) { scal[0] = red[0]; scal[1] = b_alpha[0]; }
#pragma unroll
        for (int it = 0; it < 8; ++it) {
            const int i = tid + it * 256;                 // 2048
            denom[i] = 0.0f; wsum[i] = 0.0f; out[i] = 0.0f;
        }
    }
}

// ---------------- kernel 1: bf16 MFMA GEMM + exp2 epilogue ----------------
// M=2048, N=512, K=512. ONE 16x16 fragment per wave -> 4096 waves / 1024 blocks
// = 4 blocks/CU = 4 waves/SIMD (2x the latency hiding of the 2-frag version).
// n<256  -> EQ = exp2(c*hq), TRANSPOSED quad-interleaved: EQ[(u>>2)*8192 + m*4 + (u&3)]
// n>=256 -> EK = exp2(c*hk + c*bq), row-major: EKm[m*256 + (n-256)]
__global__ __launch_bounds__(256) void qk_mfma(const unsigned short* __restrict__ hbf,
                                               const unsigned short* __restrict__ WcatT,
                                               const float* __restrict__ cbq,
                                               float* __restrict__ EQ,
                                               float* __restrict__ EKm)
{
    const int wave = (blockIdx.x * 256 + threadIdx.x) >> 6;   // 0..4095
    const int lane = threadIdx.x & 63;
    const int mt = wave >> 5;          // 0..127
    const int nt = wave & 31;          // 0..31
    const int m0 = mt * 16, n0 = nt * 16;
    const int lrow = lane & 15;
    const int kgrp = lane >> 4;        // 0..3

    f32x4 acc = {0.f, 0.f, 0.f, 0.f};
    const unsigned short* Arow = hbf   + (size_t)(m0 + lrow) * 512 + kgrp * 8;
    const unsigned short* Brow = WcatT + (size_t)(n0 + lrow) * 512 + kgrp * 8;

#pragma unroll
    for (int k0 = 0; k0 < 512; k0 += 32) {
        const bf16x8 a = *(const bf16x8*)(Arow + k0);
        const bf16x8 b = *(const bf16x8*)(Brow + k0);
        acc = __builtin_amdgcn_mfma_f32_16x16x32_bf16(a, b, acc, 0, 0, 0);
    }

    const int n_0 = n0 + lrow;
    if (nt < 16) {
#pragma unroll
        for (int r = 0; r < 4; r++) {
            const int m = m0 + kgrp * 4 + r;
            EQ[(size_t)(n_0 >> 2) * 8192 + m * 4 + (n_0 & 3)] = __builtin_amdgcn_exp2f(acc[r]);
        }
    } else {
        const float bias = cbq[n_0 - 256];
#pragma unroll
        for (int r = 0; r < 4; r++) {
            const int m = m0 + kgrp * 4 + r;
            EKm[(size_t)m * 256 + (n_0 - 256)] = __builtin_amdgcn_exp2f(acc[r] + bias);
        }
    }
}

// ---------------- kernel 2a: scores + sigmoid + exp, per-(b,t) denom ----------------
// R14 config (best total): grid (sg=128, tg=2, b=4) = 1024 blocks x 4 waves, 4 blocks/CU.
// Wave wv owns u-slice [64*wv, 64*wv+64). lane = t, FOUR t-streams. Block: 256 t x 4 s.
// Pure scalar t-form quad-rational:
//   pair: (w_a*t_b + w_b*t_a)/(t_a*t_b), t = fmaf(h,k,1); quad = 2 pairs, 1 rcp.
__global__ __launch_bounds__(256, 4) void score_kernel(const float* __restrict__ EQ,
                                                       const float* __restrict__ EKm,
                                                       const float* __restrict__ w2,
                                                       const float* __restrict__ scal,
                                                       float* __restrict__ E,
                                                       float* __restrict__ denom)
{
    const int b  = blockIdx.z;
    const int tg = blockIdx.y;          // 0..1 (256 t per block)
    const int sg = blockIdx.x;          // 0..127 (4 s per block)
    const int tid  = threadIdx.x;       // 0..255
    const int lane = tid & 63;
    const int wv = __builtin_amdgcn_readfirstlane((int)(tid >> 6));  // 0..3 = u-slice owner
    const int gbase = b * TT + tg * 256;
    const int g0 = gbase + lane;

    __shared__ __align__(16) float khk [4 * 256];          // ek rows (4 s), 4 KB
    __shared__ __align__(16) float part[4 * 4 * 4 * 64];   // [s][st][wv][lane], 16 KB

    {   // stage ek, coalesced: 4 rows x 256 floats
        const int flat = tid * 4;          // 0..1023
        const int s = flat >> 8;
        const int u = flat & 255;
        *(float4*)&khk[flat] = *(const float4*)(EKm + (size_t)(b * TT + sg * 4 + s) * 256 + u);
    }
    __syncthreads();

    float acc[4][4];   // [s][st]
#pragma unroll
    for (int s = 0; s < 4; ++s)
#pragma unroll
        for (int st = 0; st < 4; ++st) acc[s][st] = 0.0f;

    for (int sub = 0; sub < 8; ++sub) {
        const int q0 = wv * 16 + sub * 2;   // global quad index (2 quads = 8 u per sub)

        // wave-uniform weights (s_load)
        float w[2][4];
#pragma unroll
        for (int q = 0; q < 2; ++q)
#pragma unroll
            for (int j = 0; j < 4; ++j) w[q][j] = w2[(q0 + q) * 4 + j];

        // hq: 4 streams x 2 quads, coalesced b128
        f32x4 hq[4][2];
#pragma unroll
        for (int st = 0; st < 4; ++st)
#pragma unroll
            for (int q = 0; q < 2; ++q)
                hq[st][q] = *(const f32x4*)(EQ + (size_t)(q0 + q) * 8192 + (size_t)(g0 + st * 64) * 4);

#pragma unroll
        for (int s = 0; s < 4; ++s) {
#pragma unroll
            for (int q = 0; q < 2; ++q) {
                const f32x4 ekv = *(const f32x4*)&khk[s * 256 + (q0 + q) * 4];
#pragma unroll
                for (int st = 0; st < 4; ++st) {
                    const f32x4 hv = hq[st][q];
                    const float t0 = fmaf(hv[0], ekv[0], 1.0f);
                    const float t1 = fmaf(hv[1], ekv[1], 1.0f);
                    const float t2 = fmaf(hv[2], ekv[2], 1.0f);
                    const float t3 = fmaf(hv[3], ekv[3], 1.0f);
                    const float d01 = t0 * t1;
                    const float d23 = t2 * t3;
                    const float n01 = fmaf(w[q][0], t1, w[q][1] * t0);
                    const float n23 = fmaf(w[q][2], t3, w[q][3] * t2);
                    const float dq  = d01 * d23;
                    const float nq  = fmaf(n01, d23, n23 * d01);
                    const float r   = __builtin_amdgcn_rcpf(dq);
                    acc[s][st] = fmaf(nq, r, acc[s][st]);
                }
            }
        }
    }

    // write u-slice partials (lane-contiguous, conflict-free)
#pragma unroll
    for (int s = 0; s < 4; ++s)
#pragma unroll
        for (int st = 0; st < 4; ++st)
            part[((s * 4 + st) * 4 + wv) * 64 + lane] = acc[s][st];
    __syncthreads();

    // epilogue: thread tid owns t_local = tid (st = tid>>6, lane), all 4 s
    const float sumW    = scal[0];
    const float b_alpha = scal[1];
    const int est = tid >> 6;
    float Ev[4];
    float psum = 0.0f;
#pragma unroll
    for (int s = 0; s < 4; ++s) {
        const float* pp = &part[(s * 4 + est) * 4 * 64 + lane];
        float z = pp[0] + pp[64] + pp[128] + pp[192] + sumW + b_alpha;
        const float sgm = __builtin_amdgcn_rcpf(1.0f + __builtin_amdgcn_exp2f(-z * L2E));
        Ev[s] = __builtin_amdgcn_exp2f(sgm * L2E);
        psum += Ev[s];
    }
    const int grow = gbase + tid;
    *(float4*)(E + (size_t)grow * TT + sg * 4) = make_float4(Ev[0], Ev[1], Ev[2], Ev[3]);
    atomicAdd(&denom[grow], psum);
}

// ---------------- kernel 2b: wsum[b,s] = (1/T) * sum_t E[b,t,s]/denom[b,t] ----------------
__global__ __launch_bounds__(256) void colsum_kernel(const float* __restrict__ E,
                                                     const float* __restrict__ denom,
                                                     float* __restrict__ wsum)
{
    const int b  = blockIdx.y;
    const int t0 = blockIdx.x * 4;
    const int s  = threadIdx.x;
    float a0 = 0.0f, a1 = 0.0f;
#pragma unroll
    for (int ti = 0; ti < 4; ++ti) {
        const int t = t0 + ti;
        const float rd = __builtin_amdgcn_rcpf(denom[b * TT + t]);
        const float* __restrict__ Er = E + (size_t)(b * TT + t) * TT;
        a0 = fmaf(Er[s],       rd, a0);
        a1 = fmaf(Er[s + 256], rd, a1);
    }
    atomicAdd(&wsum[b * TT + s],       a0 * (1.0f / TT));
    atomicAdd(&wsum[b * TT + s + 256], a1 * (1.0f / TT));
}

// ---------------- kernel 3: out[b,:] = sum_s wsum[b,s] * h[b,s,:] ----------------
__global__ __launch_bounds__(512) void ctx_kernel(const float* __restrict__ h,
                                                  const float* __restrict__ wsum,
                                                  float* __restrict__ out)
{
    const int b  = blockIdx.y;
    const int s0 = blockIdx.x * 8;
    const int hd = threadIdx.x;
    float a = 0.0f;
#pragma unroll
    for (int si = 0; si < 8; ++si) {
        const int s = s0 + si;
        a = fmaf(wsum[b * TT + s], h[(size_t)(b * TT + s) * HH + hd], a);
    }
    atomicAdd(&out[b * HH + hd], a);
}

extern "C" void kernel_launch(void* const* d_in, const int* in_sizes, int n_in,
                              void* d_out, int out_size, void* d_ws, size_t ws_size,
                              hipStream_t stream)
{
    const float* h       = (const float*)d_in[0];
    const float* Wq      = (const float*)d_in[1];
    const float* Wk      = (const float*)d_in[2];
    const float* bq      = (const float*)d_in[3];
    const float* W       = (const float*)d_in[4];
    const float* b_alpha = (const float*)d_in[5];
    float* out = (float*)d_out;

    float* ws    = (float*)d_ws;
    float* EQ    = ws;                                   // 524,288 f32 (transposed quad-interleaved)
    float* EKm   = EQ + (size_t)524288;                  // 524,288 f32
    float* E     = EKm + (size_t)524288;                 // 1,048,576 f32
    float* denom = E + (size_t)1048576;                  // 2048
    float* wsum  = denom + BB * TT;                      // 2048
    float* w2    = wsum + BB * TT;                       // 256
    float* scal  = w2 + UU;                              // 2
    float* cbq   = scal + 2;                             // 256

    // bf16 staging aliases E (E is only written by score_kernel, after qk_mfma)
    unsigned short* hbf   = (unsigned short*)E;          // 1,048,576 bf16 = 2 MB
    unsigned short* WcatT = hbf + (size_t)1048576;       // 262,144 bf16 = 512 KB

    prep_kernel  <<<513, 256, 0, stream>>>(h, Wq, Wk, bq, W, b_alpha,
                                           hbf, WcatT, cbq, w2, scal, denom, wsum, out);
    qk_mfma      <<<1024, 256, 0, stream>>>(hbf, WcatT, cbq, EQ, EKm);
    score_kernel <<<dim3(128, 2, BB), 256, 0, stream>>>(EQ, EKm, w2, scal, E, denom);
    colsum_kernel<<<dim3(128, BB), 256, 0, stream>>>(E, denom, wsum);
    ctx_kernel   <<<dim3(64, BB), 512, 0, stream>>>(h, wsum, out);
}

// Round 19
// 62.646 us; speedup vs baseline: 1.3475x; 1.0389x over previous
//
#include <hip/hip_runtime.h>

#define BB 4
#define TT 512
#define HH 512
#define UU 256

// 2*log2(e): e^{2x} = 2^{c*x}
#define C2L2E 2.8853900817779268f
#define L2E   1.4426950408889634f

typedef __attribute__((ext_vector_type(8))) short bf16x8;
typedef __attribute__((ext_vector_type(4))) float f32x4;

static __device__ inline unsigned short f2bf(float x) {
    union { float f; unsigned u; } v; v.f = x;
    unsigned r = v.u + 0x7fff + ((v.u >> 16) & 1);   // RNE
    return (unsigned short)(r >> 16);
}

// ---------------- prep (513 blocks) ----------------
// blocks 0..255   : h -> bf16 (float4 -> ushort4, coalesced)
// blocks 256..511 : WcatT[n][k] = bf16(c*W{q,k}[k][n]) via LDS 32x32 tile transpose
// block 512       : w2/cbq/scal + zero denom/wsum/out
__global__ __launch_bounds__(256) void prep_kernel(const float* __restrict__ h,
                                                   const float* __restrict__ Wq,
                                                   const float* __restrict__ Wk,
                                                   const float* __restrict__ bq,
                                                   const float* __restrict__ W,
                                                   const float* __restrict__ b_alpha,
                                                   unsigned short* __restrict__ hbf,
                                                   unsigned short* __restrict__ WcatT,
                                                   float* __restrict__ cbq,
                                                   float* __restrict__ w2,
                                                   float* __restrict__ scal,
                                                   float* __restrict__ denom,
                                                   float* __restrict__ wsum,
                                                   float* __restrict__ out)
{
    const int blk = blockIdx.x;
    const int tid = threadIdx.x;

    if (blk < 256) {
        const int gid = blk * 256 + tid;                  // 65536 threads
#pragma unroll
        for (int it = 0; it < 4; ++it) {
            const int i = gid + it * 65536;               // 262144 float4 total
            const float4 v = ((const float4*)h)[i];
            ushort4 o;
            o.x = f2bf(v.x); o.y = f2bf(v.y); o.z = f2bf(v.z); o.w = f2bf(v.w);
            ((ushort4*)hbf)[i] = o;
        }
    } else if (blk < 512) {
        __shared__ unsigned short lds[32][33];
        const int tile = blk - 256;                       // 0..255
        const int tn = tile & 15;                         // n-tile
        const int tk = tile >> 4;                         // k-tile
        const int lx = tid & 31;
        const int ly = tid >> 5;                          // 0..7
        const int n = tn * 32 + lx;
#pragma unroll
        for (int kk = ly; kk < 32; kk += 8) {
            const int k = tk * 32 + kk;
            const float v = (n < 256) ? Wq[k * UU + n] : Wk[k * UU + (n - 256)];
            lds[lx][kk] = f2bf(C2L2E * v);
        }
        __syncthreads();
#pragma unroll
        for (int nn = ly; nn < 32; nn += 8) {
            WcatT[(size_t)(tn * 32 + nn) * 512 + tk * 32 + lx] = lds[nn][lx];
        }
    } else {
        __shared__ float red[256];
        const float w = W[tid];
        w2[tid] = -2.0f * w;
        red[tid] = w;
        cbq[tid] = C2L2E * bq[tid];
        __syncthreads();
        for (int off = 128; off > 0; off >>= 1) {
            if (tid < off) red[tid] += red[tid + off];
            __syncthreads();
        }
        if (tid == 0) { scal[0] = red[0]; scal[1] = b_alpha[0]; }
#pragma unroll
        for (int it = 0; it < 8; ++it) {
            const int i = tid + it * 256;                 // 2048
            denom[i] = 0.0f; wsum[i] = 0.0f; out[i] = 0.0f;
        }
    }
}

// ---------------- kernel 1: bf16 MFMA GEMM + exp2 epilogue (R14 2-frag) ----------------
// M=2048, N=512, K=512.
// n<256  -> EQ = exp2(c*hq), TRANSPOSED quad-interleaved: EQ[(u>>2)*8192 + m*4 + (u&3)]
// n>=256 -> EK = exp2(c*hk + c*bq), row-major: EKm[m*256 + (n-256)]
__global__ __launch_bounds__(256) void qk_mfma(const unsigned short* __restrict__ hbf,
                                               const unsigned short* __restrict__ WcatT,
                                               const float* __restrict__ cbq,
                                               float* __restrict__ EQ,
                                               float* __restrict__ EKm)
{
    const int wave = (blockIdx.x * 256 + threadIdx.x) >> 6;   // 0..2047
    const int lane = threadIdx.x & 63;
    const int mt = wave >> 4;          // 0..127
    const int nt = wave & 15;          // 0..15
    const int m0 = mt * 16, n0 = nt * 32;
    const int lrow = lane & 15;
    const int kgrp = lane >> 4;        // 0..3

    f32x4 acc0 = {0.f, 0.f, 0.f, 0.f};
    f32x4 acc1 = {0.f, 0.f, 0.f, 0.f};
    const unsigned short* Arow = hbf   + (size_t)(m0 + lrow) * 512 + kgrp * 8;
    const unsigned short* B0   = WcatT + (size_t)(n0 + lrow) * 512 + kgrp * 8;
    const unsigned short* B1   = B0 + (size_t)16 * 512;

#pragma unroll
    for (int k0 = 0; k0 < 512; k0 += 32) {
        const bf16x8 a  = *(const bf16x8*)(Arow + k0);
        const bf16x8 b0 = *(const bf16x8*)(B0 + k0);
        const bf16x8 b1 = *(const bf16x8*)(B1 + k0);
        acc0 = __builtin_amdgcn_mfma_f32_16x16x32_bf16(a, b0, acc0, 0, 0, 0);
        acc1 = __builtin_amdgcn_mfma_f32_16x16x32_bf16(a, b1, acc1, 0, 0, 0);
    }

    const int n_0 = n0 + lrow;
    const int n_1 = n_0 + 16;
    if (nt < 8) {
#pragma unroll
        for (int r = 0; r < 4; r++) {
            const int m = m0 + kgrp * 4 + r;
            EQ[(size_t)(n_0 >> 2) * 8192 + m * 4 + (n_0 & 3)] = __builtin_amdgcn_exp2f(acc0[r]);
            EQ[(size_t)(n_1 >> 2) * 8192 + m * 4 + (n_1 & 3)] = __builtin_amdgcn_exp2f(acc1[r]);
        }
    } else {
        const float bias0 = cbq[n_0 - 256];
        const float bias1 = cbq[n_1 - 256];
#pragma unroll
        for (int r = 0; r < 4; r++) {
            const int m = m0 + kgrp * 4 + r;
            EKm[(size_t)m * 256 + (n_0 - 256)] = __builtin_amdgcn_exp2f(acc0[r] + bias0);
            EKm[(size_t)m * 256 + (n_1 - 256)] = __builtin_amdgcn_exp2f(acc1[r] + bias1);
        }
    }
}

// ---------------- kernel 2a: scores + sigmoid + exp, per-(b,t) denom ----------------
// R14 config (measured best): grid (sg=128, tg=2, b=4) = 1024 blocks x 4 waves, 4 blocks/CU.
// Wave wv owns u-slice [64*wv, 64*wv+64). lane = t, FOUR t-streams. Block: 256 t x 4 s.
// Inner math pure scalar t-form quad-rational:
//   pair: (w_a*t_b + w_b*t_a)/(t_a*t_b), t = fmaf(h,k,1); quad = 2 pairs, 1 rcp.
__global__ __launch_bounds__(256, 4) void score_kernel(const float* __restrict__ EQ,
                                                       const float* __restrict__ EKm,
                                                       const float* __restrict__ w2,
                                                       const float* __restrict__ scal,
                                                       float* __restrict__ E,
                                                       float* __restrict__ denom)
{
    const int b  = blockIdx.z;
    const int tg = blockIdx.y;          // 0..1 (256 t per block)
    const int sg = blockIdx.x;          // 0..127 (4 s per block)
    const int tid  = threadIdx.x;       // 0..255
    const int lane = tid & 63;
    const int wv = __builtin_amdgcn_readfirstlane((int)(tid >> 6));  // 0..3 = u-slice owner
    const int gbase = b * TT + tg * 256;
    const int g0 = gbase + lane;

    __shared__ __align__(16) float khk [4 * 256];          // ek rows (4 s), 4 KB
    __shared__ __align__(16) float part[4 * 4 * 4 * 64];   // [s][st][wv][lane], 16 KB

    {   // stage ek, coalesced: 4 rows x 256 floats
        const int flat = tid * 4;          // 0..1023
        const int s = flat >> 8;
        const int u = flat & 255;
        *(float4*)&khk[flat] = *(const float4*)(EKm + (size_t)(b * TT + sg * 4 + s) * 256 + u);
    }
    __syncthreads();

    float acc[4][4];   // [s][st]
#pragma unroll
    for (int s = 0; s < 4; ++s)
#pragma unroll
        for (int st = 0; st < 4; ++st) acc[s][st] = 0.0f;

    for (int sub = 0; sub < 8; ++sub) {
        const int q0 = wv * 16 + sub * 2;   // global quad index (2 quads = 8 u per sub)

        // wave-uniform weights (s_load)
        float w[2][4];
#pragma unroll
        for (int q = 0; q < 2; ++q)
#pragma unroll
            for (int j = 0; j < 4; ++j) w[q][j] = w2[(q0 + q) * 4 + j];

        // hq: 4 streams x 2 quads, coalesced b128
        f32x4 hq[4][2];
#pragma unroll
        for (int st = 0; st < 4; ++st)
#pragma unroll
            for (int q = 0; q < 2; ++q)
                hq[st][q] = *(const f32x4*)(EQ + (size_t)(q0 + q) * 8192 + (size_t)(g0 + st * 64) * 4);

#pragma unroll
        for (int s = 0; s < 4; ++s) {
#pragma unroll
            for (int q = 0; q < 2; ++q) {
                const f32x4 ekv = *(const f32x4*)&khk[s * 256 + (q0 + q) * 4];
#pragma unroll
                for (int st = 0; st < 4; ++st) {
                    const f32x4 hv = hq[st][q];
                    const float t0 = fmaf(hv[0], ekv[0], 1.0f);
                    const float t1 = fmaf(hv[1], ekv[1], 1.0f);
                    const float t2 = fmaf(hv[2], ekv[2], 1.0f);
                    const float t3 = fmaf(hv[3], ekv[3], 1.0f);
                    const float d01 = t0 * t1;
                    const float d23 = t2 * t3;
                    const float n01 = fmaf(w[q][0], t1, w[q][1] * t0);
                    const float n23 = fmaf(w[q][2], t3, w[q][3] * t2);
                    const float dq  = d01 * d23;
                    const float nq  = fmaf(n01, d23, n23 * d01);
                    const float r   = __builtin_amdgcn_rcpf(dq);
                    acc[s][st] = fmaf(nq, r, acc[s][st]);
                }
            }
        }
    }

    // write u-slice partials (lane-contiguous, conflict-free)
#pragma unroll
    for (int s = 0; s < 4; ++s)
#pragma unroll
        for (int st = 0; st < 4; ++st)
            part[((s * 4 + st) * 4 + wv) * 64 + lane] = acc[s][st];
    __syncthreads();

    // epilogue: thread tid owns t_local = tid (st = tid>>6, lane), all 4 s
    const float sumW    = scal[0];
    const float b_alpha = scal[1];
    const int est = tid >> 6;
    float Ev[4];
    float psum = 0.0f;
#pragma unroll
    for (int s = 0; s < 4; ++s) {
        const float* pp = &part[(s * 4 + est) * 4 * 64 + lane];
        float z = pp[0] + pp[64] + pp[128] + pp[192] + sumW + b_alpha;
        const float sgm = __builtin_amdgcn_rcpf(1.0f + __builtin_amdgcn_exp2f(-z * L2E));
        Ev[s] = __builtin_amdgcn_exp2f(sgm * L2E);
        psum += Ev[s];
    }
    const int grow = gbase + tid;
    *(float4*)(E + (size_t)grow * TT + sg * 4) = make_float4(Ev[0], Ev[1], Ev[2], Ev[3]);
    atomicAdd(&denom[grow], psum);
}

// ---------------- kernel 2b: wsum[b,s] = (1/T) * sum_t E[b,t,s]/denom[b,t] ----------------
__global__ __launch_bounds__(256) void colsum_kernel(const float* __restrict__ E,
                                                     const float* __restrict__ denom,
                                                     float* __restrict__ wsum)
{
    const int b  = blockIdx.y;
    const int t0 = blockIdx.x * 4;
    const int s  = threadIdx.x;
    float a0 = 0.0f, a1 = 0.0f;
#pragma unroll
    for (int ti = 0; ti < 4; ++ti) {
        const int t = t0 + ti;
        const float rd = __builtin_amdgcn_rcpf(denom[b * TT + t]);
        const float* __restrict__ Er = E + (size_t)(b * TT + t) * TT;
        a0 = fmaf(Er[s],       rd, a0);
        a1 = fmaf(Er[s + 256], rd, a1);
    }
    atomicAdd(&wsum[b * TT + s],       a0 * (1.0f / TT));
    atomicAdd(&wsum[b * TT + s + 256], a1 * (1.0f / TT));
}

// ---------------- kernel 3: out[b,:] = sum_s wsum[b,s] * h[b,s,:] ----------------
__global__ __launch_bounds__(512) void ctx_kernel(const float* __restrict__ h,
                                                  const float* __restrict__ wsum,
                                                  float* __restrict__ out)
{
    const int b  = blockIdx.y;
    const int s0 = blockIdx.x * 8;
    const int hd = threadIdx.x;
    float a = 0.0f;
#pragma unroll
    for (int si = 0; si < 8; ++si) {
        const int s = s0 + si;
        a = fmaf(wsum[b * TT + s], h[(size_t)(b * TT + s) * HH + hd], a);
    }
    atomicAdd(&out[b * HH + hd], a);
}

extern "C" void kernel_launch(void* const* d_in, const int* in_sizes, int n_in,
                              void* d_out, int out_size, void* d_ws, size_t ws_size,
                              hipStream_t stream)
{
    const float* h       = (const float*)d_in[0];
    const float* Wq      = (const float*)d_in[1];
    const float* Wk      = (const float*)d_in[2];
    const float* bq      = (const float*)d_in[3];
    const float* W       = (const float*)d_in[4];
    const float* b_alpha = (const float*)d_in[5];
    float* out = (float*)d_out;

    float* ws    = (float*)d_ws;
    float* EQ    = ws;                                   // 524,288 f32 (transposed quad-interleaved)
    float* EKm   = EQ + (size_t)524288;                  // 524,288 f32
    float* E     = EKm + (size_t)524288;                 // 1,048,576 f32
    float* denom = E + (size_t)1048576;                  // 2048
    float* wsum  = denom + BB * TT;                      // 2048
    float* w2    = wsum + BB * TT;                       // 256
    float* scal  = w2 + UU;                              // 2
    float* cbq   = scal + 2;                             // 256

    // bf16 staging aliases E (E is only written by score_kernel, after qk_mfma)
    unsigned short* hbf   = (unsigned short*)E;          // 1,048,576 bf16 = 2 MB
    unsigned short* WcatT = hbf + (size_t)1048576;       // 262,144 bf16 = 512 KB

    prep_kernel  <<<513, 256, 0, stream>>>(h, Wq, Wk, bq, W, b_alpha,
                                           hbf, WcatT, cbq, w2, scal, denom, wsum, out);
    qk_mfma      <<<512, 256, 0, stream>>>(hbf, WcatT, cbq, EQ, EKm);
    score_kernel <<<dim3(128, 2, BB), 256, 0, stream>>>(EQ, EKm, w2, scal, E, denom);
    colsum_kernel<<<dim3(128, BB), 256, 0, stream>>>(E, denom, wsum);
    ctx_kernel   <<<dim3(64, BB), 512, 0, stream>>>(h, wsum, out);
}